// Round 11
// baseline (1502.271 us; speedup 1.0000x reference)
//
#include <hip/hip_runtime.h>

typedef unsigned short u16;
typedef unsigned int u32;

#define HID 128

static inline int cdiv(long long a, int b) { return (int)((a + b - 1) / b); }

__device__ __forceinline__ float bfbits(u32 u) { union { u32 u; float f; } c; c.u = u; return c.f; }
__device__ __forceinline__ u16 f2bf(float f) {
  union { float f; u32 u; } c; c.f = f;
  u32 u = c.u;
  return (u16)((u + 0x7fffu + ((u >> 16) & 1u)) >> 16);  // RNE
}
__device__ __forceinline__ u32 pack2bf(float a, float b) {
  return (u32)f2bf(a) | ((u32)f2bf(b) << 16);
}

// ---------- GEMM + attention epilogue (unchanged) ----------
template <int COUT, int HEADS>
__global__ __launch_bounds__(256) void gemm_attn(
    const float* __restrict__ Hin, const float* __restrict__ W,
    const float* __restrict__ attS, const float* __restrict__ attD,
    u16* __restrict__ XL, float* __restrict__ aS, float* __restrict__ aD, int n) {
  constexpr int TN = COUT / 8;
  constexpr int TM = 256 / TN;
  constexpr int MT = TM * 8;
  constexpr int HALF = COUT / 2;
  constexpr int C = COUT / HEADS;
  constexpr bool SAMEHEAD = (HALF < C);

  __shared__ float xs[32][MT + 4];
  __shared__ float ws[32][COUT];

  int t = threadIdx.x;
  int tx = t % TN, ty = t / TN;
  int rowBase = blockIdx.x * MT;

  float acc[8][8];
#pragma unroll
  for (int r = 0; r < 8; ++r)
#pragma unroll
    for (int c = 0; c < 8; ++c) acc[r][c] = 0.f;

  for (int kb = 0; kb < 4; ++kb) {
    __syncthreads();
    {
      int kg = (t & 7) * 4;
#pragma unroll
      for (int pass = 0; pass < MT / 32; ++pass) {
        int rr = pass * 32 + (t >> 3);
        int grow = rowBase + rr;
        float4 v = make_float4(0.f, 0.f, 0.f, 0.f);
        if (grow < n) v = *(const float4*)(Hin + (size_t)grow * HID + kb * 32 + kg);
        xs[kg + 0][rr] = v.x;
        xs[kg + 1][rr] = v.y;
        xs[kg + 2][rr] = v.z;
        xs[kg + 3][rr] = v.w;
      }
    }
    {
      constexpr int WF = 32 * COUT / 256;
      const float* wp = W + (size_t)kb * 32 * COUT;
      float* wsf = &ws[0][0];
#pragma unroll
      for (int u = 0; u < WF; u += 4) {
        int idx = t * WF + u;
        *(float4*)(wsf + idx) = *(const float4*)(wp + idx);
      }
    }
    __syncthreads();
#pragma unroll 8
    for (int k = 0; k < 32; ++k) {
      const float4 xv0 = *(const float4*)&xs[k][ty * 8];
      const float4 xv1 = *(const float4*)&xs[k][ty * 8 + 4];
      const float4 wv0 = *(const float4*)&ws[k][tx * 4];
      const float4 wv1 = *(const float4*)&ws[k][HALF + tx * 4];
      const float xr[8] = {xv0.x, xv0.y, xv0.z, xv0.w, xv1.x, xv1.y, xv1.z, xv1.w};
      const float wc[8] = {wv0.x, wv0.y, wv0.z, wv0.w, wv1.x, wv1.y, wv1.z, wv1.w};
#pragma unroll
      for (int r = 0; r < 8; ++r)
#pragma unroll
        for (int c = 0; c < 8; ++c) acc[r][c] += xr[r] * wc[c];
    }
  }

  float sv[8], dv[8];
#pragma unroll
  for (int j = 0; j < 4; ++j) {
    sv[j] = attS[tx * 4 + j];
    sv[4 + j] = attS[HALF + tx * 4 + j];
    dv[j] = attD[tx * 4 + j];
    dv[4 + j] = attD[HALF + tx * 4 + j];
  }
  int row0 = rowBase + ty * 8;
  int hlo = (tx * 4) / C;
  int hhi = (HALF + tx * 4) / C;
  u32* XLo = (u32*)XL;
#pragma unroll
  for (int r = 0; r < 8; ++r) {
    int row = row0 + r;
    bool ok = (row < n);
    if (ok) {
      u32 lo01 = pack2bf(acc[r][0], acc[r][1]);
      u32 lo23 = pack2bf(acc[r][2], acc[r][3]);
      u32 hi01 = pack2bf(acc[r][4], acc[r][5]);
      u32 hi23 = pack2bf(acc[r][6], acc[r][7]);
      *(uint2*)(XLo + (size_t)row * (COUT / 2) + tx * 2) = make_uint2(lo01, lo23);
      *(uint2*)(XLo + (size_t)row * (COUT / 2) + COUT / 4 + tx * 2) = make_uint2(hi01, hi23);
    }
    float pslo = acc[r][0] * sv[0] + acc[r][1] * sv[1] + acc[r][2] * sv[2] + acc[r][3] * sv[3];
    float pshi = acc[r][4] * sv[4] + acc[r][5] * sv[5] + acc[r][6] * sv[6] + acc[r][7] * sv[7];
    float pdlo = acc[r][0] * dv[0] + acc[r][1] * dv[1] + acc[r][2] * dv[2] + acc[r][3] * dv[3];
    float pdhi = acc[r][4] * dv[4] + acc[r][5] * dv[5] + acc[r][6] * dv[6] + acc[r][7] * dv[7];
    if (SAMEHEAD) { pslo += pshi; pdlo += pdhi; }
#pragma unroll
    for (int mk = 1; mk < 8; mk <<= 1) {
      pslo += __shfl_xor(pslo, mk);
      pdlo += __shfl_xor(pdlo, mk);
      if (!SAMEHEAD) {
        pshi += __shfl_xor(pshi, mk);
        pdhi += __shfl_xor(pdhi, mk);
      }
    }
    if (((tx & 7) == 0) && ok) {
      aS[(size_t)row * HEADS + hlo] = pslo;
      aD[(size_t)row * HEADS + hlo] = pdlo;
      if (!SAMEHEAD) {
        aS[(size_t)row * HEADS + hhi] = pshi;
        aD[(size_t)row * HEADS + hhi] = pdhi;
      }
    }
  }
}

// ================= bucket-sort CSR build (bucket = dst>>8, 256 nodes/bucket) =================

// per-bucket histogram, LDS-privatized. blockIdx.y = layer.
__global__ __launch_bounds__(256) void bucket_hist(const int* __restrict__ ei,
                                                   int* __restrict__ bucketCnt,
                                                   int e4, int rem, int E, int NB) {
  int L = blockIdx.y;
  const int* dst = ei + (size_t)(2 * L + 1) * E;
  __shared__ int h[512];
  int t = threadIdx.x;
  for (int b = t; b < NB; b += 256) h[b] = 0;
  __syncthreads();
  int i = blockIdx.x * blockDim.x + t;
  if (i < e4) {
    int4 d = ((const int4*)dst)[i];
    atomicAdd(&h[d.x >> 8], 1);
    atomicAdd(&h[d.y >> 8], 1);
    atomicAdd(&h[d.z >> 8], 1);
    atomicAdd(&h[d.w >> 8], 1);
  } else if (i - e4 < rem) {
    atomicAdd(&h[dst[e4 * 4 + (i - e4)] >> 8], 1);
  }
  __syncthreads();
  for (int b = t; b < NB; b += 256) {
    int v = h[b];
    if (v) atomicAdd(&bucketCnt[L * NB + b], v);
  }
}

// exclusive scan of NB bucket counts per layer. grid = 3 blocks (one per layer).
__global__ __launch_bounds__(256) void bucket_scan(const int* __restrict__ bucketCnt,
                                                   int* __restrict__ bucketOff,
                                                   int* __restrict__ bucketCur, int NB, int E) {
  int L = blockIdx.x;
  int t = threadIdx.x;
  int lane = t & 63, wid = t >> 6;
  __shared__ int wpart[4];
  __shared__ int carry;
  if (t == 0) carry = 0;
  __syncthreads();
  for (int s = 0; s < NB; s += 256) {
    int v = (s + t < NB) ? bucketCnt[L * NB + s + t] : 0;
    int inc = v;
#pragma unroll
    for (int off = 1; off < 64; off <<= 1) {
      int w = __shfl_up(inc, (unsigned)off, 64);
      if (lane >= off) inc += w;
    }
    if (lane == 63) wpart[wid] = inc;
    __syncthreads();
    if (t == 0) {
      int a = 0;
#pragma unroll
      for (int k = 0; k < 4; ++k) { int tmp = wpart[k]; wpart[k] = a; a += tmp; }
    }
    __syncthreads();
    int ex = carry + wpart[wid] + inc - v;
    if (s + t < NB) {
      bucketOff[L * (NB + 1) + s + t] = ex;
      bucketCur[L * NB + s + t] = ex;
    }
    __syncthreads();
    if (t == 255) carry += wpart[3] + inc;
    __syncthreads();
  }
  if (t == 0) bucketOff[L * (NB + 1) + NB] = E;
}

// append (src,dst) pairs into bucket-grouped array. Only NB frontiers per layer -> L2-resident.
__global__ __launch_bounds__(256) void bucket_scatter(const int* __restrict__ ei,
                                                      int* __restrict__ bucketCur,
                                                      int2* __restrict__ pairsAll,
                                                      int e4, int rem, int E, int NB) {
  int L = blockIdx.y;
  const int* src = ei + (size_t)(2 * L) * E;
  const int* dst = src + E;
  int2* pairs = pairsAll + (size_t)L * E;
  int* cur = bucketCur + L * NB;
  int i = blockIdx.x * blockDim.x + threadIdx.x;
  if (i < e4) {
    int4 s = ((const int4*)src)[i];
    int4 d = ((const int4*)dst)[i];
    int p0 = atomicAdd(&cur[d.x >> 8], 1);
    int p1 = atomicAdd(&cur[d.y >> 8], 1);
    int p2 = atomicAdd(&cur[d.z >> 8], 1);
    int p3 = atomicAdd(&cur[d.w >> 8], 1);
    pairs[p0] = make_int2(s.x, d.x);
    pairs[p1] = make_int2(s.y, d.y);
    pairs[p2] = make_int2(s.z, d.z);
    pairs[p3] = make_int2(s.w, d.w);
  } else if (i - e4 < rem) {
    int k = e4 * 4 + (i - e4);
    int d = dst[k];
    int p = atomicAdd(&cur[d >> 8], 1);
    pairs[p] = make_int2(src[k], d);
  }
}

// one block per (bucket, layer): per-node counts/scan/cursors in LDS; writes indptr
// (coalesced), self-loop at segment head, and edges into a contiguous region.
__global__ __launch_bounds__(256) void csr_finalize(const int2* __restrict__ pairsAll,
                                                    const int* __restrict__ bucketOff,
                                                    int* __restrict__ indptrAll,
                                                    int* __restrict__ srcIdxAll,
                                                    int N, int E, int NB) {
  int L = blockIdx.y, b = blockIdx.x;
  const int2* pairs = pairsAll + (size_t)L * E;
  int* indptr = indptrAll + (size_t)L * (N + 1);
  int* srcL = srcIdxAll + (size_t)L * (E + N);
  int base = b << 8;
  int nodes = min(256, N - base);
  int p0 = bucketOff[L * (NB + 1) + b];
  int p1 = bucketOff[L * (NB + 1) + b + 1];

  __shared__ int cnt[256];
  __shared__ int wpart[4];
  int t = threadIdx.x;
  int lane = t & 63, wid = t >> 6;
  cnt[t] = 0;
  __syncthreads();

  // pass A: per-node degree within bucket
  for (int i = p0 + t; i < p1; i += 256) atomicAdd(&cnt[pairs[i].y - base], 1);
  __syncthreads();

  // pass B: exclusive scan of (cnt+1) over nodes
  int v = (t < nodes) ? cnt[t] + 1 : 0;
  int inc = v;
#pragma unroll
  for (int off = 1; off < 64; off <<= 1) {
    int w = __shfl_up(inc, (unsigned)off, 64);
    if (lane >= off) inc += w;
  }
  if (lane == 63) wpart[wid] = inc;
  __syncthreads();
  if (t == 0) {
    int a = 0;
#pragma unroll
    for (int k = 0; k < 4; ++k) { int tmp = wpart[k]; wpart[k] = a; a += tmp; }
  }
  __syncthreads();
  int ex = wpart[wid] + inc - v;
  __syncthreads();  // all reads of cnt done before overwrite below
  if (t < nodes) {
    int segStart = p0 + base + ex;  // edges before bucket + self-loops before bucket + local
    indptr[base + t] = segStart;
    srcL[segStart] = base + t;  // self loop first in segment
    cnt[t] = segStart + 1;      // cursor
  }
  if (b == NB - 1 && t == 0) indptr[N] = E + N;
  __syncthreads();

  // pass C: place edges (contiguous region per bucket)
  for (int i = p0 + t; i < p1; i += 256) {
    int2 pr = pairs[i];
    int p = atomicAdd(&cnt[pr.y - base], 1);
    srcL[p] = pr.x;
  }
}

// ---------- aggregation (unchanged) ----------
template <int COUT, int HEADS, bool RELU>
__global__ __launch_bounds__(256) void aggregate(
    const u16* __restrict__ XL, const float* __restrict__ aS, const float* __restrict__ aD,
    const int* __restrict__ indptr, const int* __restrict__ srcIdx,
    const float* __restrict__ bias, float* __restrict__ outF, int n) {
  constexpr int VPL = COUT / 64;
  constexpr int C = COUT / HEADS;
  int wave = (blockIdx.x * blockDim.x + threadIdx.x) >> 6;
  if (wave >= n) return;
  int lane = threadIdx.x & 63;
  int i = wave;
  int col = lane * VPL;
  int h = col / C;
  float ad = aD[i * HEADS + h];
  float s = 0.f, acc0 = 0.f, acc1 = 0.f;
  int e0 = indptr[i], e1 = indptr[i + 1];
  int idx = e0;
  const u32* XL32 = (const u32*)XL;

  for (; idx + 8 <= e1; idx += 8) {
    int j[8];
#pragma unroll
    for (int u = 0; u < 8; ++u) j[u] = srcIdx[idx + u];
    float a[8];
#pragma unroll
    for (int u = 0; u < 8; ++u) a[u] = aS[j[u] * HEADS + h];
    if (VPL == 2) {
      u32 px[8];
#pragma unroll
      for (int u = 0; u < 8; ++u) px[u] = XL32[j[u] * (COUT / 2) + lane];
#pragma unroll
      for (int u = 0; u < 8; ++u) {
        float l = a[u] + ad;
        l = (l >= 0.f) ? l : 0.2f * l;
        float el = __expf(fminf(l, 60.f));
        s += el;
        acc0 += el * bfbits(px[u] << 16);
        acc1 += el * bfbits(px[u] & 0xffff0000u);
      }
    } else {
      u16 px[8];
#pragma unroll
      for (int u = 0; u < 8; ++u) px[u] = XL[j[u] * COUT + lane];
#pragma unroll
      for (int u = 0; u < 8; ++u) {
        float l = a[u] + ad;
        l = (l >= 0.f) ? l : 0.2f * l;
        float el = __expf(fminf(l, 60.f));
        s += el;
        acc0 += el * bfbits(((u32)px[u]) << 16);
      }
    }
  }
  for (; idx < e1; ++idx) {
    int j = srcIdx[idx];
    float l = aS[j * HEADS + h] + ad;
    l = (l >= 0.f) ? l : 0.2f * l;
    float el = __expf(fminf(l, 60.f));
    s += el;
    if (VPL == 2) {
      u32 px = XL32[j * (COUT / 2) + lane];
      acc0 += el * bfbits(px << 16);
      acc1 += el * bfbits(px & 0xffff0000u);
    } else {
      acc0 += el * bfbits(((u32)XL[j * COUT + lane]) << 16);
    }
  }

  float inv = 1.f / (s + 1e-16f);
  float o0 = acc0 * inv + bias[col];
  if (RELU) o0 = fmaxf(o0, 0.f);
  if (VPL == 2) {
    float o1 = acc1 * inv + bias[col + 1];
    if (RELU) o1 = fmaxf(o1, 0.f);
    *(float2*)(outF + ((size_t)i * COUT + col)) = make_float2(o0, o1);
  } else {
    outF[(size_t)i * COUT + col] = o0;
  }
}

extern "C" void kernel_launch(void* const* d_in, const int* in_sizes, int n_in,
                              void* d_out, int out_size, void* d_ws, size_t ws_size,
                              hipStream_t stream) {
  const float* x = (const float*)d_in[0];
  const int* ei = (const int*)d_in[1];
  const float* W1 = (const float*)d_in[2];
  const float* as1 = (const float*)d_in[3];
  const float* ad1 = (const float*)d_in[4];
  const float* b1 = (const float*)d_in[5];
  const float* W2 = (const float*)d_in[6];
  const float* as2 = (const float*)d_in[7];
  const float* ad2 = (const float*)d_in[8];
  const float* b2 = (const float*)d_in[9];
  const float* W3 = (const float*)d_in[10];
  const float* as3 = (const float*)d_in[11];
  const float* ad3 = (const float*)d_in[12];
  const float* b3 = (const float*)d_in[13];

  int N = in_sizes[0] / HID;  // x is [N,128]
  int E = in_sizes[1] / 6;    // edge_indices is [3,2,E]
  int NB = cdiv(N, 256);      // buckets of 256 nodes

  char* w = (char*)d_ws;
  auto alloc = [&](size_t bytes) {
    void* q = (void*)w;
    w += (bytes + 255) & ~(size_t)255;
    return q;
  };
  float* bufH = (float*)alloc((size_t)N * HID * 4);
  u16* bufXL = (u16*)alloc((size_t)N * HID * 2);
  float* aS = (float*)alloc((size_t)N * 4 * 4);
  float* aD = (float*)alloc((size_t)N * 4 * 4);
  int* bucketCnt = (int*)alloc((size_t)3 * NB * 4);
  int* bucketOff = (int*)alloc((size_t)3 * (NB + 1) * 4);
  int* bucketCur = (int*)alloc((size_t)3 * NB * 4);
  int2* pairsAll = (int2*)alloc((size_t)3 * E * 8);
  int* indptrAll = (int*)alloc((size_t)3 * (N + 1) * 4);
  int* srcIdxAll = (int*)alloc((size_t)3 * (E + N) * 4);

  int e4 = E >> 2, rem = E & 3;

  // ---- bucket-sort CSR build for all 3 layers ----
  hipMemsetAsync(bucketCnt, 0, (size_t)3 * NB * 4, stream);
  {
    dim3 g(cdiv((long long)e4 + rem, 256), 3);
    bucket_hist<<<g, 256, 0, stream>>>(ei, bucketCnt, e4, rem, E, NB);
  }
  bucket_scan<<<3, 256, 0, stream>>>(bucketCnt, bucketOff, bucketCur, NB, E);
  {
    dim3 g(cdiv((long long)e4 + rem, 256), 3);
    bucket_scatter<<<g, 256, 0, stream>>>(ei, bucketCur, pairsAll, e4, rem, E, NB);
  }
  {
    dim3 g(NB, 3);
    csr_finalize<<<g, 256, 0, stream>>>(pairsAll, bucketOff, indptrAll, srcIdxAll, N, E, NB);
  }

  // ---- layer 1 ----
  gemm_attn<128, 4><<<cdiv(N, 128), 256, 0, stream>>>(x, W1, as1, ad1, bufXL, aS, aD, N);
  aggregate<128, 4, true><<<cdiv(N, 4), 256, 0, stream>>>(
      bufXL, aS, aD, indptrAll, srcIdxAll, b1, bufH, N);
  // ---- layer 2 ----
  gemm_attn<128, 4><<<cdiv(N, 128), 256, 0, stream>>>(bufH, W2, as2, ad2, bufXL, aS, aD, N);
  aggregate<128, 4, true><<<cdiv(N, 4), 256, 0, stream>>>(
      bufXL, aS, aD, indptrAll + (N + 1), srcIdxAll + (size_t)(E + N), b2, bufH, N);
  // ---- layer 3 ----
  gemm_attn<64, 1><<<cdiv(N, 256), 256, 0, stream>>>(bufH, W3, as3, ad3, bufXL, aS, aD, N);
  aggregate<64, 1, false><<<cdiv(N, 4), 256, 0, stream>>>(
      bufXL, aS, aD, indptrAll + 2 * (N + 1), srcIdxAll + (size_t)2 * (E + N), b3,
      (float*)d_out, N);
}

// Round 12
// 386.155 us; speedup vs baseline: 3.8903x; 3.8903x over previous
//
#include <hip/hip_runtime.h>

typedef unsigned short u16;
typedef unsigned int u32;

#define HID 128

static inline int cdiv(long long a, int b) { return (int)((a + b - 1) / b); }

__device__ __forceinline__ float bfbits(u32 u) { union { u32 u; float f; } c; c.u = u; return c.f; }
__device__ __forceinline__ u16 f2bf(float f) {
  union { float f; u32 u; } c; c.f = f;
  u32 u = c.u;
  return (u16)((u + 0x7fffu + ((u >> 16) & 1u)) >> 16);  // RNE
}
__device__ __forceinline__ u32 pack2bf(float a, float b) {
  return (u32)f2bf(a) | ((u32)f2bf(b) << 16);
}

// ---------- GEMM + attention epilogue (unchanged) ----------
template <int COUT, int HEADS>
__global__ __launch_bounds__(256) void gemm_attn(
    const float* __restrict__ Hin, const float* __restrict__ W,
    const float* __restrict__ attS, const float* __restrict__ attD,
    u16* __restrict__ XL, float* __restrict__ aS, float* __restrict__ aD, int n) {
  constexpr int TN = COUT / 8;
  constexpr int TM = 256 / TN;
  constexpr int MT = TM * 8;
  constexpr int HALF = COUT / 2;
  constexpr int C = COUT / HEADS;
  constexpr bool SAMEHEAD = (HALF < C);

  __shared__ float xs[32][MT + 4];
  __shared__ float ws[32][COUT];

  int t = threadIdx.x;
  int tx = t % TN, ty = t / TN;
  int rowBase = blockIdx.x * MT;

  float acc[8][8];
#pragma unroll
  for (int r = 0; r < 8; ++r)
#pragma unroll
    for (int c = 0; c < 8; ++c) acc[r][c] = 0.f;

  for (int kb = 0; kb < 4; ++kb) {
    __syncthreads();
    {
      int kg = (t & 7) * 4;
#pragma unroll
      for (int pass = 0; pass < MT / 32; ++pass) {
        int rr = pass * 32 + (t >> 3);
        int grow = rowBase + rr;
        float4 v = make_float4(0.f, 0.f, 0.f, 0.f);
        if (grow < n) v = *(const float4*)(Hin + (size_t)grow * HID + kb * 32 + kg);
        xs[kg + 0][rr] = v.x;
        xs[kg + 1][rr] = v.y;
        xs[kg + 2][rr] = v.z;
        xs[kg + 3][rr] = v.w;
      }
    }
    {
      constexpr int WF = 32 * COUT / 256;
      const float* wp = W + (size_t)kb * 32 * COUT;
      float* wsf = &ws[0][0];
#pragma unroll
      for (int u = 0; u < WF; u += 4) {
        int idx = t * WF + u;
        *(float4*)(wsf + idx) = *(const float4*)(wp + idx);
      }
    }
    __syncthreads();
#pragma unroll 8
    for (int k = 0; k < 32; ++k) {
      const float4 xv0 = *(const float4*)&xs[k][ty * 8];
      const float4 xv1 = *(const float4*)&xs[k][ty * 8 + 4];
      const float4 wv0 = *(const float4*)&ws[k][tx * 4];
      const float4 wv1 = *(const float4*)&ws[k][HALF + tx * 4];
      const float xr[8] = {xv0.x, xv0.y, xv0.z, xv0.w, xv1.x, xv1.y, xv1.z, xv1.w};
      const float wc[8] = {wv0.x, wv0.y, wv0.z, wv0.w, wv1.x, wv1.y, wv1.z, wv1.w};
#pragma unroll
      for (int r = 0; r < 8; ++r)
#pragma unroll
        for (int c = 0; c < 8; ++c) acc[r][c] += xr[r] * wc[c];
    }
  }

  float sv[8], dv[8];
#pragma unroll
  for (int j = 0; j < 4; ++j) {
    sv[j] = attS[tx * 4 + j];
    sv[4 + j] = attS[HALF + tx * 4 + j];
    dv[j] = attD[tx * 4 + j];
    dv[4 + j] = attD[HALF + tx * 4 + j];
  }
  int row0 = rowBase + ty * 8;
  int hlo = (tx * 4) / C;
  int hhi = (HALF + tx * 4) / C;
  u32* XLo = (u32*)XL;
#pragma unroll
  for (int r = 0; r < 8; ++r) {
    int row = row0 + r;
    bool ok = (row < n);
    if (ok) {
      u32 lo01 = pack2bf(acc[r][0], acc[r][1]);
      u32 lo23 = pack2bf(acc[r][2], acc[r][3]);
      u32 hi01 = pack2bf(acc[r][4], acc[r][5]);
      u32 hi23 = pack2bf(acc[r][6], acc[r][7]);
      *(uint2*)(XLo + (size_t)row * (COUT / 2) + tx * 2) = make_uint2(lo01, lo23);
      *(uint2*)(XLo + (size_t)row * (COUT / 2) + COUT / 4 + tx * 2) = make_uint2(hi01, hi23);
    }
    float pslo = acc[r][0] * sv[0] + acc[r][1] * sv[1] + acc[r][2] * sv[2] + acc[r][3] * sv[3];
    float pshi = acc[r][4] * sv[4] + acc[r][5] * sv[5] + acc[r][6] * sv[6] + acc[r][7] * sv[7];
    float pdlo = acc[r][0] * dv[0] + acc[r][1] * dv[1] + acc[r][2] * dv[2] + acc[r][3] * dv[3];
    float pdhi = acc[r][4] * dv[4] + acc[r][5] * dv[5] + acc[r][6] * dv[6] + acc[r][7] * dv[7];
    if (SAMEHEAD) { pslo += pshi; pdlo += pdhi; }
#pragma unroll
    for (int mk = 1; mk < 8; mk <<= 1) {
      pslo += __shfl_xor(pslo, mk);
      pdlo += __shfl_xor(pdlo, mk);
      if (!SAMEHEAD) {
        pshi += __shfl_xor(pshi, mk);
        pdhi += __shfl_xor(pdhi, mk);
      }
    }
    if (((tx & 7) == 0) && ok) {
      aS[(size_t)row * HEADS + hlo] = pslo;
      aD[(size_t)row * HEADS + hlo] = pdlo;
      if (!SAMEHEAD) {
        aS[(size_t)row * HEADS + hhi] = pshi;
        aD[(size_t)row * HEADS + hhi] = pdhi;
      }
    }
  }
}

// ============ bucket-sort CSR build, contention-fixed ============
// bucket = dst>>8 (256 nodes/bucket), NB<=256. Global bucket counters are
// PADDED to 64B (stride 16 ints) and receive ONE atomic per (bucket,block)
// via LDS block aggregation. Each block covers 4096 edges (1024 int4 groups).
#define PSTR 16  // padding stride (ints) for per-bucket counters

__global__ __launch_bounds__(256) void bucket_hist(const int* __restrict__ ei,
                                                   int* __restrict__ cntP,
                                                   int e4, int rem, int E, int NB) {
  int L = blockIdx.y;
  const int* dst = ei + (size_t)(2 * L + 1) * E;
  __shared__ int cnt[256];
  int t = threadIdx.x;
  cnt[t] = 0;
  __syncthreads();
  int gbase = blockIdx.x * 1024 + t;
#pragma unroll
  for (int u = 0; u < 4; ++u) {
    int g = gbase + u * 256;
    if (g < e4) {
      int4 d = *(const int4*)(dst + g * 4);
      atomicAdd(&cnt[d.x >> 8], 1);
      atomicAdd(&cnt[d.y >> 8], 1);
      atomicAdd(&cnt[d.z >> 8], 1);
      atomicAdd(&cnt[d.w >> 8], 1);
    }
  }
  if (blockIdx.x == 0 && t < rem) atomicAdd(&cnt[dst[e4 * 4 + t] >> 8], 1);
  __syncthreads();
  int c = cnt[t];
  if (t < NB && c > 0) atomicAdd(&cntP[(L * NB + t) * PSTR], c);
}

// exclusive scan of padded counts -> bucketOff (unpadded) + padded cursor init.
__global__ __launch_bounds__(256) void bucket_scan(const int* __restrict__ cntP,
                                                   int* __restrict__ bucketOff,
                                                   int* __restrict__ curP, int NB, int E) {
  int L = blockIdx.x;
  int t = threadIdx.x;
  int lane = t & 63, wid = t >> 6;
  __shared__ int wpart[4];
  int v = (t < NB) ? cntP[(L * NB + t) * PSTR] : 0;
  int inc = v;
#pragma unroll
  for (int off = 1; off < 64; off <<= 1) {
    int w = __shfl_up(inc, (unsigned)off, 64);
    if (lane >= off) inc += w;
  }
  if (lane == 63) wpart[wid] = inc;
  __syncthreads();
  if (t == 0) {
    int a = 0;
#pragma unroll
    for (int k = 0; k < 4; ++k) { int tmp = wpart[k]; wpart[k] = a; a += tmp; }
  }
  __syncthreads();
  int ex = wpart[wid] + inc - v;
  if (t < NB) {
    bucketOff[L * (NB + 1) + t] = ex;
    curP[(L * NB + t) * PSTR] = ex;
  }
  if (t == 0) bucketOff[L * (NB + 1) + NB] = E;
}

// two-pass block-aggregated scatter: edges held in registers.
__global__ __launch_bounds__(256) void bucket_scatter(const int* __restrict__ ei,
                                                      int* __restrict__ curP,
                                                      int2* __restrict__ pairsAll,
                                                      int e4, int rem, int E, int NB) {
  int L = blockIdx.y;
  const int* src = ei + (size_t)(2 * L) * E;
  const int* dst = src + E;
  int2* pairs = pairsAll + (size_t)L * E;
  __shared__ int cnt[256];
  __shared__ int baseS[256];
  int t = threadIdx.x;
  cnt[t] = 0;
  __syncthreads();

  int gbase = blockIdx.x * 1024 + t;
  int4 dv[4], sv[4];
  bool val[4];
#pragma unroll
  for (int u = 0; u < 4; ++u) {
    int g = gbase + u * 256;
    val[u] = (g < e4);
    if (val[u]) {
      dv[u] = *(const int4*)(dst + g * 4);
      sv[u] = *(const int4*)(src + g * 4);
      atomicAdd(&cnt[dv[u].x >> 8], 1);
      atomicAdd(&cnt[dv[u].y >> 8], 1);
      atomicAdd(&cnt[dv[u].z >> 8], 1);
      atomicAdd(&cnt[dv[u].w >> 8], 1);
    }
  }
  int tailS = 0, tailD = 0;
  bool hasTail = (blockIdx.x == 0 && t < rem);
  if (hasTail) {
    tailD = dst[e4 * 4 + t];
    tailS = src[e4 * 4 + t];
    atomicAdd(&cnt[tailD >> 8], 1);
  }
  __syncthreads();
  int c = cnt[t];
  if (t < NB && c > 0) baseS[t] = atomicAdd(&curP[(L * NB + t) * PSTR], c);
  __syncthreads();
  cnt[t] = 0;  // reuse as local offset
  __syncthreads();
#pragma unroll
  for (int u = 0; u < 4; ++u) {
    if (val[u]) {
      int b, p;
      b = dv[u].x >> 8; p = atomicAdd(&cnt[b], 1); pairs[baseS[b] + p] = make_int2(sv[u].x, dv[u].x);
      b = dv[u].y >> 8; p = atomicAdd(&cnt[b], 1); pairs[baseS[b] + p] = make_int2(sv[u].y, dv[u].y);
      b = dv[u].z >> 8; p = atomicAdd(&cnt[b], 1); pairs[baseS[b] + p] = make_int2(sv[u].z, dv[u].z);
      b = dv[u].w >> 8; p = atomicAdd(&cnt[b], 1); pairs[baseS[b] + p] = make_int2(sv[u].w, dv[u].w);
    }
  }
  if (hasTail) {
    int b = tailD >> 8;
    int p = atomicAdd(&cnt[b], 1);
    pairs[baseS[b] + p] = make_int2(tailS, tailD);
  }
}

// one block per (bucket, layer): per-node scan/cursors in LDS; emits indptr,
// self-loop at segment head, edges into contiguous region. (unchanged)
__global__ __launch_bounds__(256) void csr_finalize(const int2* __restrict__ pairsAll,
                                                    const int* __restrict__ bucketOff,
                                                    int* __restrict__ indptrAll,
                                                    int* __restrict__ srcIdxAll,
                                                    int N, int E, int NB) {
  int L = blockIdx.y, b = blockIdx.x;
  const int2* pairs = pairsAll + (size_t)L * E;
  int* indptr = indptrAll + (size_t)L * (N + 1);
  int* srcL = srcIdxAll + (size_t)L * (E + N);
  int base = b << 8;
  int nodes = min(256, N - base);
  int p0 = bucketOff[L * (NB + 1) + b];
  int p1 = bucketOff[L * (NB + 1) + b + 1];

  __shared__ int cnt[256];
  __shared__ int wpart[4];
  int t = threadIdx.x;
  int lane = t & 63, wid = t >> 6;
  cnt[t] = 0;
  __syncthreads();

  for (int i = p0 + t; i < p1; i += 256) atomicAdd(&cnt[pairs[i].y - base], 1);
  __syncthreads();

  int v = (t < nodes) ? cnt[t] + 1 : 0;
  int inc = v;
#pragma unroll
  for (int off = 1; off < 64; off <<= 1) {
    int w = __shfl_up(inc, (unsigned)off, 64);
    if (lane >= off) inc += w;
  }
  if (lane == 63) wpart[wid] = inc;
  __syncthreads();
  if (t == 0) {
    int a = 0;
#pragma unroll
    for (int k = 0; k < 4; ++k) { int tmp = wpart[k]; wpart[k] = a; a += tmp; }
  }
  __syncthreads();
  int ex = wpart[wid] + inc - v;
  __syncthreads();
  if (t < nodes) {
    int segStart = p0 + base + ex;
    indptr[base + t] = segStart;
    srcL[segStart] = base + t;
    cnt[t] = segStart + 1;
  }
  if (b == NB - 1 && t == 0) indptr[N] = E + N;
  __syncthreads();

  for (int i = p0 + t; i < p1; i += 256) {
    int2 pr = pairs[i];
    int p = atomicAdd(&cnt[pr.y - base], 1);
    srcL[p] = pr.x;
  }
}

// ---------- aggregation (unchanged) ----------
template <int COUT, int HEADS, bool RELU>
__global__ __launch_bounds__(256) void aggregate(
    const u16* __restrict__ XL, const float* __restrict__ aS, const float* __restrict__ aD,
    const int* __restrict__ indptr, const int* __restrict__ srcIdx,
    const float* __restrict__ bias, float* __restrict__ outF, int n) {
  constexpr int VPL = COUT / 64;
  constexpr int C = COUT / HEADS;
  int wave = (blockIdx.x * blockDim.x + threadIdx.x) >> 6;
  if (wave >= n) return;
  int lane = threadIdx.x & 63;
  int i = wave;
  int col = lane * VPL;
  int h = col / C;
  float ad = aD[i * HEADS + h];
  float s = 0.f, acc0 = 0.f, acc1 = 0.f;
  int e0 = indptr[i], e1 = indptr[i + 1];
  int idx = e0;
  const u32* XL32 = (const u32*)XL;

  for (; idx + 8 <= e1; idx += 8) {
    int j[8];
#pragma unroll
    for (int u = 0; u < 8; ++u) j[u] = srcIdx[idx + u];
    float a[8];
#pragma unroll
    for (int u = 0; u < 8; ++u) a[u] = aS[j[u] * HEADS + h];
    if (VPL == 2) {
      u32 px[8];
#pragma unroll
      for (int u = 0; u < 8; ++u) px[u] = XL32[j[u] * (COUT / 2) + lane];
#pragma unroll
      for (int u = 0; u < 8; ++u) {
        float l = a[u] + ad;
        l = (l >= 0.f) ? l : 0.2f * l;
        float el = __expf(fminf(l, 60.f));
        s += el;
        acc0 += el * bfbits(px[u] << 16);
        acc1 += el * bfbits(px[u] & 0xffff0000u);
      }
    } else {
      u16 px[8];
#pragma unroll
      for (int u = 0; u < 8; ++u) px[u] = XL[j[u] * COUT + lane];
#pragma unroll
      for (int u = 0; u < 8; ++u) {
        float l = a[u] + ad;
        l = (l >= 0.f) ? l : 0.2f * l;
        float el = __expf(fminf(l, 60.f));
        s += el;
        acc0 += el * bfbits(((u32)px[u]) << 16);
      }
    }
  }
  for (; idx < e1; ++idx) {
    int j = srcIdx[idx];
    float l = aS[j * HEADS + h] + ad;
    l = (l >= 0.f) ? l : 0.2f * l;
    float el = __expf(fminf(l, 60.f));
    s += el;
    if (VPL == 2) {
      u32 px = XL32[j * (COUT / 2) + lane];
      acc0 += el * bfbits(px << 16);
      acc1 += el * bfbits(px & 0xffff0000u);
    } else {
      acc0 += el * bfbits(((u32)XL[j * COUT + lane]) << 16);
    }
  }

  float inv = 1.f / (s + 1e-16f);
  float o0 = acc0 * inv + bias[col];
  if (RELU) o0 = fmaxf(o0, 0.f);
  if (VPL == 2) {
    float o1 = acc1 * inv + bias[col + 1];
    if (RELU) o1 = fmaxf(o1, 0.f);
    *(float2*)(outF + ((size_t)i * COUT + col)) = make_float2(o0, o1);
  } else {
    outF[(size_t)i * COUT + col] = o0;
  }
}

extern "C" void kernel_launch(void* const* d_in, const int* in_sizes, int n_in,
                              void* d_out, int out_size, void* d_ws, size_t ws_size,
                              hipStream_t stream) {
  const float* x = (const float*)d_in[0];
  const int* ei = (const int*)d_in[1];
  const float* W1 = (const float*)d_in[2];
  const float* as1 = (const float*)d_in[3];
  const float* ad1 = (const float*)d_in[4];
  const float* b1 = (const float*)d_in[5];
  const float* W2 = (const float*)d_in[6];
  const float* as2 = (const float*)d_in[7];
  const float* ad2 = (const float*)d_in[8];
  const float* b2 = (const float*)d_in[9];
  const float* W3 = (const float*)d_in[10];
  const float* as3 = (const float*)d_in[11];
  const float* ad3 = (const float*)d_in[12];
  const float* b3 = (const float*)d_in[13];

  int N = in_sizes[0] / HID;  // x is [N,128]
  int E = in_sizes[1] / 6;    // edge_indices is [3,2,E]
  int NB = cdiv(N, 256);      // buckets of 256 nodes (NB <= 256 assumed)

  char* w = (char*)d_ws;
  auto alloc = [&](size_t bytes) {
    void* q = (void*)w;
    w += (bytes + 255) & ~(size_t)255;
    return q;
  };
  float* bufH = (float*)alloc((size_t)N * HID * 4);
  u16* bufXL = (u16*)alloc((size_t)N * HID * 2);
  float* aS = (float*)alloc((size_t)N * 4 * 4);
  float* aD = (float*)alloc((size_t)N * 4 * 4);
  int* cntP = (int*)alloc((size_t)3 * NB * PSTR * 4);
  int* curP = (int*)alloc((size_t)3 * NB * PSTR * 4);
  int* bucketOff = (int*)alloc((size_t)3 * (NB + 1) * 4);
  int2* pairsAll = (int2*)alloc((size_t)3 * E * 8);
  int* indptrAll = (int*)alloc((size_t)3 * (N + 1) * 4);
  int* srcIdxAll = (int*)alloc((size_t)3 * (E + N) * 4);

  int e4 = E >> 2, rem = E & 3;
  int gx = cdiv(e4, 1024);  // 4096 edges per block

  // ---- CSR build for all 3 layers ----
  hipMemsetAsync(cntP, 0, (size_t)3 * NB * PSTR * 4, stream);
  {
    dim3 g(gx, 3);
    bucket_hist<<<g, 256, 0, stream>>>(ei, cntP, e4, rem, E, NB);
  }
  bucket_scan<<<3, 256, 0, stream>>>(cntP, bucketOff, curP, NB, E);
  {
    dim3 g(gx, 3);
    bucket_scatter<<<g, 256, 0, stream>>>(ei, curP, pairsAll, e4, rem, E, NB);
  }
  {
    dim3 g(NB, 3);
    csr_finalize<<<g, 256, 0, stream>>>(pairsAll, bucketOff, indptrAll, srcIdxAll, N, E, NB);
  }

  // ---- layer 1 ----
  gemm_attn<128, 4><<<cdiv(N, 128), 256, 0, stream>>>(x, W1, as1, ad1, bufXL, aS, aD, N);
  aggregate<128, 4, true><<<cdiv(N, 4), 256, 0, stream>>>(
      bufXL, aS, aD, indptrAll, srcIdxAll, b1, bufH, N);
  // ---- layer 2 ----
  gemm_attn<128, 4><<<cdiv(N, 128), 256, 0, stream>>>(bufH, W2, as2, ad2, bufXL, aS, aD, N);
  aggregate<128, 4, true><<<cdiv(N, 4), 256, 0, stream>>>(
      bufXL, aS, aD, indptrAll + (N + 1), srcIdxAll + (size_t)(E + N), b2, bufH, N);
  // ---- layer 3 ----
  gemm_attn<64, 1><<<cdiv(N, 256), 256, 0, stream>>>(bufH, W3, as3, ad3, bufXL, aS, aD, N);
  aggregate<64, 1, false><<<cdiv(N, 4), 256, 0, stream>>>(
      bufXL, aS, aD, indptrAll + 2 * (N + 1), srcIdxAll + (size_t)2 * (E + N), b3,
      (float*)d_out, N);
}

// Round 13
// 357.075 us; speedup vs baseline: 4.2072x; 1.0814x over previous
//
#include <hip/hip_runtime.h>

typedef unsigned short u16;
typedef unsigned int u32;

#define HID 128

static inline int cdiv(long long a, int b) { return (int)((a + b - 1) / b); }

__device__ __forceinline__ float bfbits(u32 u) { union { u32 u; float f; } c; c.u = u; return c.f; }
__device__ __forceinline__ u16 f2bf(float f) {
  union { float f; u32 u; } c; c.f = f;
  u32 u = c.u;
  return (u16)((u + 0x7fffu + ((u >> 16) & 1u)) >> 16);  // RNE
}
__device__ __forceinline__ u32 pack2bf(float a, float b) {
  return (u32)f2bf(a) | ((u32)f2bf(b) << 16);
}

// ---------- GEMM + attention epilogue (unchanged) ----------
template <int COUT, int HEADS>
__global__ __launch_bounds__(256) void gemm_attn(
    const float* __restrict__ Hin, const float* __restrict__ W,
    const float* __restrict__ attS, const float* __restrict__ attD,
    u16* __restrict__ XL, float* __restrict__ aS, float* __restrict__ aD, int n) {
  constexpr int TN = COUT / 8;
  constexpr int TM = 256 / TN;
  constexpr int MT = TM * 8;
  constexpr int HALF = COUT / 2;
  constexpr int C = COUT / HEADS;
  constexpr bool SAMEHEAD = (HALF < C);

  __shared__ float xs[32][MT + 4];
  __shared__ float ws[32][COUT];

  int t = threadIdx.x;
  int tx = t % TN, ty = t / TN;
  int rowBase = blockIdx.x * MT;

  float acc[8][8];
#pragma unroll
  for (int r = 0; r < 8; ++r)
#pragma unroll
    for (int c = 0; c < 8; ++c) acc[r][c] = 0.f;

  for (int kb = 0; kb < 4; ++kb) {
    __syncthreads();
    {
      int kg = (t & 7) * 4;
#pragma unroll
      for (int pass = 0; pass < MT / 32; ++pass) {
        int rr = pass * 32 + (t >> 3);
        int grow = rowBase + rr;
        float4 v = make_float4(0.f, 0.f, 0.f, 0.f);
        if (grow < n) v = *(const float4*)(Hin + (size_t)grow * HID + kb * 32 + kg);
        xs[kg + 0][rr] = v.x;
        xs[kg + 1][rr] = v.y;
        xs[kg + 2][rr] = v.z;
        xs[kg + 3][rr] = v.w;
      }
    }
    {
      constexpr int WF = 32 * COUT / 256;
      const float* wp = W + (size_t)kb * 32 * COUT;
      float* wsf = &ws[0][0];
#pragma unroll
      for (int u = 0; u < WF; u += 4) {
        int idx = t * WF + u;
        *(float4*)(wsf + idx) = *(const float4*)(wp + idx);
      }
    }
    __syncthreads();
#pragma unroll 8
    for (int k = 0; k < 32; ++k) {
      const float4 xv0 = *(const float4*)&xs[k][ty * 8];
      const float4 xv1 = *(const float4*)&xs[k][ty * 8 + 4];
      const float4 wv0 = *(const float4*)&ws[k][tx * 4];
      const float4 wv1 = *(const float4*)&ws[k][HALF + tx * 4];
      const float xr[8] = {xv0.x, xv0.y, xv0.z, xv0.w, xv1.x, xv1.y, xv1.z, xv1.w};
      const float wc[8] = {wv0.x, wv0.y, wv0.z, wv0.w, wv1.x, wv1.y, wv1.z, wv1.w};
#pragma unroll
      for (int r = 0; r < 8; ++r)
#pragma unroll
        for (int c = 0; c < 8; ++c) acc[r][c] += xr[r] * wc[c];
    }
  }

  float sv[8], dv[8];
#pragma unroll
  for (int j = 0; j < 4; ++j) {
    sv[j] = attS[tx * 4 + j];
    sv[4 + j] = attS[HALF + tx * 4 + j];
    dv[j] = attD[tx * 4 + j];
    dv[4 + j] = attD[HALF + tx * 4 + j];
  }
  int row0 = rowBase + ty * 8;
  int hlo = (tx * 4) / C;
  int hhi = (HALF + tx * 4) / C;
  u32* XLo = (u32*)XL;
#pragma unroll
  for (int r = 0; r < 8; ++r) {
    int row = row0 + r;
    bool ok = (row < n);
    if (ok) {
      u32 lo01 = pack2bf(acc[r][0], acc[r][1]);
      u32 lo23 = pack2bf(acc[r][2], acc[r][3]);
      u32 hi01 = pack2bf(acc[r][4], acc[r][5]);
      u32 hi23 = pack2bf(acc[r][6], acc[r][7]);
      *(uint2*)(XLo + (size_t)row * (COUT / 2) + tx * 2) = make_uint2(lo01, lo23);
      *(uint2*)(XLo + (size_t)row * (COUT / 2) + COUT / 4 + tx * 2) = make_uint2(hi01, hi23);
    }
    float pslo = acc[r][0] * sv[0] + acc[r][1] * sv[1] + acc[r][2] * sv[2] + acc[r][3] * sv[3];
    float pshi = acc[r][4] * sv[4] + acc[r][5] * sv[5] + acc[r][6] * sv[6] + acc[r][7] * sv[7];
    float pdlo = acc[r][0] * dv[0] + acc[r][1] * dv[1] + acc[r][2] * dv[2] + acc[r][3] * dv[3];
    float pdhi = acc[r][4] * dv[4] + acc[r][5] * dv[5] + acc[r][6] * dv[6] + acc[r][7] * dv[7];
    if (SAMEHEAD) { pslo += pshi; pdlo += pdhi; }
#pragma unroll
    for (int mk = 1; mk < 8; mk <<= 1) {
      pslo += __shfl_xor(pslo, mk);
      pdlo += __shfl_xor(pdlo, mk);
      if (!SAMEHEAD) {
        pshi += __shfl_xor(pshi, mk);
        pdhi += __shfl_xor(pdhi, mk);
      }
    }
    if (((tx & 7) == 0) && ok) {
      aS[(size_t)row * HEADS + hlo] = pslo;
      aD[(size_t)row * HEADS + hlo] = pdlo;
      if (!SAMEHEAD) {
        aS[(size_t)row * HEADS + hhi] = pshi;
        aD[(size_t)row * HEADS + hhi] = pdhi;
      }
    }
  }
}

// ============ bucket-sort CSR build (unchanged from round 12) ============
#define PSTR 16  // padding stride (ints) for per-bucket counters

__global__ __launch_bounds__(256) void bucket_hist(const int* __restrict__ ei,
                                                   int* __restrict__ cntP,
                                                   int e4, int rem, int E, int NB) {
  int L = blockIdx.y;
  const int* dst = ei + (size_t)(2 * L + 1) * E;
  __shared__ int cnt[256];
  int t = threadIdx.x;
  cnt[t] = 0;
  __syncthreads();
  int gbase = blockIdx.x * 1024 + t;
#pragma unroll
  for (int u = 0; u < 4; ++u) {
    int g = gbase + u * 256;
    if (g < e4) {
      int4 d = *(const int4*)(dst + g * 4);
      atomicAdd(&cnt[d.x >> 8], 1);
      atomicAdd(&cnt[d.y >> 8], 1);
      atomicAdd(&cnt[d.z >> 8], 1);
      atomicAdd(&cnt[d.w >> 8], 1);
    }
  }
  if (blockIdx.x == 0 && t < rem) atomicAdd(&cnt[dst[e4 * 4 + t] >> 8], 1);
  __syncthreads();
  int c = cnt[t];
  if (t < NB && c > 0) atomicAdd(&cntP[(L * NB + t) * PSTR], c);
}

__global__ __launch_bounds__(256) void bucket_scan(const int* __restrict__ cntP,
                                                   int* __restrict__ bucketOff,
                                                   int* __restrict__ curP, int NB, int E) {
  int L = blockIdx.x;
  int t = threadIdx.x;
  int lane = t & 63, wid = t >> 6;
  __shared__ int wpart[4];
  int v = (t < NB) ? cntP[(L * NB + t) * PSTR] : 0;
  int inc = v;
#pragma unroll
  for (int off = 1; off < 64; off <<= 1) {
    int w = __shfl_up(inc, (unsigned)off, 64);
    if (lane >= off) inc += w;
  }
  if (lane == 63) wpart[wid] = inc;
  __syncthreads();
  if (t == 0) {
    int a = 0;
#pragma unroll
    for (int k = 0; k < 4; ++k) { int tmp = wpart[k]; wpart[k] = a; a += tmp; }
  }
  __syncthreads();
  int ex = wpart[wid] + inc - v;
  if (t < NB) {
    bucketOff[L * (NB + 1) + t] = ex;
    curP[(L * NB + t) * PSTR] = ex;
  }
  if (t == 0) bucketOff[L * (NB + 1) + NB] = E;
}

__global__ __launch_bounds__(256) void bucket_scatter(const int* __restrict__ ei,
                                                      int* __restrict__ curP,
                                                      int2* __restrict__ pairsAll,
                                                      int e4, int rem, int E, int NB) {
  int L = blockIdx.y;
  const int* src = ei + (size_t)(2 * L) * E;
  const int* dst = src + E;
  int2* pairs = pairsAll + (size_t)L * E;
  __shared__ int cnt[256];
  __shared__ int baseS[256];
  int t = threadIdx.x;
  cnt[t] = 0;
  __syncthreads();

  int gbase = blockIdx.x * 1024 + t;
  int4 dv[4], sv[4];
  bool val[4];
#pragma unroll
  for (int u = 0; u < 4; ++u) {
    int g = gbase + u * 256;
    val[u] = (g < e4);
    if (val[u]) {
      dv[u] = *(const int4*)(dst + g * 4);
      sv[u] = *(const int4*)(src + g * 4);
      atomicAdd(&cnt[dv[u].x >> 8], 1);
      atomicAdd(&cnt[dv[u].y >> 8], 1);
      atomicAdd(&cnt[dv[u].z >> 8], 1);
      atomicAdd(&cnt[dv[u].w >> 8], 1);
    }
  }
  int tailS = 0, tailD = 0;
  bool hasTail = (blockIdx.x == 0 && t < rem);
  if (hasTail) {
    tailD = dst[e4 * 4 + t];
    tailS = src[e4 * 4 + t];
    atomicAdd(&cnt[tailD >> 8], 1);
  }
  __syncthreads();
  int c = cnt[t];
  if (t < NB && c > 0) baseS[t] = atomicAdd(&curP[(L * NB + t) * PSTR], c);
  __syncthreads();
  cnt[t] = 0;  // reuse as local offset
  __syncthreads();
#pragma unroll
  for (int u = 0; u < 4; ++u) {
    if (val[u]) {
      int b, p;
      b = dv[u].x >> 8; p = atomicAdd(&cnt[b], 1); pairs[baseS[b] + p] = make_int2(sv[u].x, dv[u].x);
      b = dv[u].y >> 8; p = atomicAdd(&cnt[b], 1); pairs[baseS[b] + p] = make_int2(sv[u].y, dv[u].y);
      b = dv[u].z >> 8; p = atomicAdd(&cnt[b], 1); pairs[baseS[b] + p] = make_int2(sv[u].z, dv[u].z);
      b = dv[u].w >> 8; p = atomicAdd(&cnt[b], 1); pairs[baseS[b] + p] = make_int2(sv[u].w, dv[u].w);
    }
  }
  if (hasTail) {
    int b = tailD >> 8;
    int p = atomicAdd(&cnt[b], 1);
    pairs[baseS[b] + p] = make_int2(tailS, tailD);
  }
}

__global__ __launch_bounds__(256) void csr_finalize(const int2* __restrict__ pairsAll,
                                                    const int* __restrict__ bucketOff,
                                                    int* __restrict__ indptrAll,
                                                    int* __restrict__ srcIdxAll,
                                                    int N, int E, int NB) {
  int L = blockIdx.y, b = blockIdx.x;
  const int2* pairs = pairsAll + (size_t)L * E;
  int* indptr = indptrAll + (size_t)L * (N + 1);
  int* srcL = srcIdxAll + (size_t)L * (E + N);
  int base = b << 8;
  int nodes = min(256, N - base);
  int p0 = bucketOff[L * (NB + 1) + b];
  int p1 = bucketOff[L * (NB + 1) + b + 1];

  __shared__ int cnt[256];
  __shared__ int wpart[4];
  int t = threadIdx.x;
  int lane = t & 63, wid = t >> 6;
  cnt[t] = 0;
  __syncthreads();

  for (int i = p0 + t; i < p1; i += 256) atomicAdd(&cnt[pairs[i].y - base], 1);
  __syncthreads();

  int v = (t < nodes) ? cnt[t] + 1 : 0;
  int inc = v;
#pragma unroll
  for (int off = 1; off < 64; off <<= 1) {
    int w = __shfl_up(inc, (unsigned)off, 64);
    if (lane >= off) inc += w;
  }
  if (lane == 63) wpart[wid] = inc;
  __syncthreads();
  if (t == 0) {
    int a = 0;
#pragma unroll
    for (int k = 0; k < 4; ++k) { int tmp = wpart[k]; wpart[k] = a; a += tmp; }
  }
  __syncthreads();
  int ex = wpart[wid] + inc - v;
  __syncthreads();
  if (t < nodes) {
    int segStart = p0 + base + ex;
    indptr[base + t] = segStart;
    srcL[segStart] = base + t;
    cnt[t] = segStart + 1;
  }
  if (b == NB - 1 && t == 0) indptr[N] = E + N;
  __syncthreads();

  for (int i = p0 + t; i < p1; i += 256) {
    int2 pr = pairs[i];
    int p = atomicAdd(&cnt[pr.y - base], 1);
    srcL[p] = pr.x;
  }
}

// ---------- aggregation: wave = node, G edges per instruction ----------
// Lane = (group g, col-lane cl). Each lane covers VPL=8 cols (one uint4 of
// packed bf16). COUT=128: G=4 edges x 16 lanes; COUT=64: G=8 edges x 8 lanes.
// Softmax scalar path (logit/leaky/exp) is computed once per edge per LPG
// lanes instead of per 64 — ~4x less redundant VALU than one-edge-per-inst.
// Epilogue: shfl_xor reduce of acc+s across groups; group 0 writes.
template <int COUT, int HEADS, bool RELU>
__global__ __launch_bounds__(256) void aggregate(
    const u16* __restrict__ XL, const float* __restrict__ aS, const float* __restrict__ aD,
    const int* __restrict__ indptr, const int* __restrict__ srcIdx,
    const float* __restrict__ bias, float* __restrict__ outF, int n) {
  constexpr int VPL = 8;           // cols per lane
  constexpr int LPG = COUT / VPL;  // lanes per edge-group (16 or 8)
  constexpr int G = 64 / LPG;      // edges per batch (4 or 8)
  constexpr int C = COUT / HEADS;
  int wave = (blockIdx.x * blockDim.x + threadIdx.x) >> 6;
  if (wave >= n) return;
  int lane = threadIdx.x & 63;
  int g = lane / LPG;
  int cl = lane % LPG;
  int col0 = cl * VPL;
  int h = col0 / C;
  int i = wave;
  float ad = aD[i * HEADS + h];
  float s = 0.f;
  float acc[VPL];
#pragma unroll
  for (int v = 0; v < VPL; ++v) acc[v] = 0.f;
  int e0 = indptr[i], e1 = indptr[i + 1];
  const u32* XL32 = (const u32*)XL;

  auto doEdge = [&](int loadIdx, bool act) {
    int j = srcIdx[loadIdx];  // broadcast within group
    float a = aS[j * HEADS + h];
    uint4 px = *(const uint4*)(XL32 + j * (COUT / 2) + cl * 4);
    float l = a + ad;
    l = (l >= 0.f) ? l : 0.2f * l;
    float el = act ? __expf(fminf(l, 60.f)) : 0.f;
    s += el;
    acc[0] += el * bfbits(px.x << 16);
    acc[1] += el * bfbits(px.x & 0xffff0000u);
    acc[2] += el * bfbits(px.y << 16);
    acc[3] += el * bfbits(px.y & 0xffff0000u);
    acc[4] += el * bfbits(px.z << 16);
    acc[5] += el * bfbits(px.z & 0xffff0000u);
    acc[6] += el * bfbits(px.w << 16);
    acc[7] += el * bfbits(px.w & 0xffff0000u);
  };

  int idx = e0;
  for (; idx + 2 * G <= e1; idx += 2 * G) {  // two independent batches in flight
    doEdge(idx + g, true);
    doEdge(idx + G + g, true);
  }
  for (; idx + G <= e1; idx += G) doEdge(idx + g, true);
  int r = e1 - idx;
  if (r > 0) doEdge((g < r) ? (idx + g) : e0, g < r);  // e0 slot (self-loop) is safe

  // reduce acc + s across the G groups (lane bits log2(LPG)..5)
#pragma unroll
  for (int mk = LPG; mk < 64; mk <<= 1) {
    s += __shfl_xor(s, mk);
#pragma unroll
    for (int v = 0; v < VPL; ++v) acc[v] += __shfl_xor(acc[v], mk);
  }

  if (g == 0) {
    float inv = 1.f / (s + 1e-16f);
    float o[VPL];
#pragma unroll
    for (int v = 0; v < VPL; ++v) {
      o[v] = acc[v] * inv + bias[col0 + v];
      if (RELU) o[v] = fmaxf(o[v], 0.f);
    }
    float* op = outF + (size_t)i * COUT + col0;
    *(float4*)op = make_float4(o[0], o[1], o[2], o[3]);
    *(float4*)(op + 4) = make_float4(o[4], o[5], o[6], o[7]);
  }
}

extern "C" void kernel_launch(void* const* d_in, const int* in_sizes, int n_in,
                              void* d_out, int out_size, void* d_ws, size_t ws_size,
                              hipStream_t stream) {
  const float* x = (const float*)d_in[0];
  const int* ei = (const int*)d_in[1];
  const float* W1 = (const float*)d_in[2];
  const float* as1 = (const float*)d_in[3];
  const float* ad1 = (const float*)d_in[4];
  const float* b1 = (const float*)d_in[5];
  const float* W2 = (const float*)d_in[6];
  const float* as2 = (const float*)d_in[7];
  const float* ad2 = (const float*)d_in[8];
  const float* b2 = (const float*)d_in[9];
  const float* W3 = (const float*)d_in[10];
  const float* as3 = (const float*)d_in[11];
  const float* ad3 = (const float*)d_in[12];
  const float* b3 = (const float*)d_in[13];

  int N = in_sizes[0] / HID;  // x is [N,128]
  int E = in_sizes[1] / 6;    // edge_indices is [3,2,E]
  int NB = cdiv(N, 256);      // buckets of 256 nodes (NB <= 256 assumed)

  char* w = (char*)d_ws;
  auto alloc = [&](size_t bytes) {
    void* q = (void*)w;
    w += (bytes + 255) & ~(size_t)255;
    return q;
  };
  float* bufH = (float*)alloc((size_t)N * HID * 4);
  u16* bufXL = (u16*)alloc((size_t)N * HID * 2);
  float* aS = (float*)alloc((size_t)N * 4 * 4);
  float* aD = (float*)alloc((size_t)N * 4 * 4);
  int* cntP = (int*)alloc((size_t)3 * NB * PSTR * 4);
  int* curP = (int*)alloc((size_t)3 * NB * PSTR * 4);
  int* bucketOff = (int*)alloc((size_t)3 * (NB + 1) * 4);
  int2* pairsAll = (int2*)alloc((size_t)3 * E * 8);
  int* indptrAll = (int*)alloc((size_t)3 * (N + 1) * 4);
  int* srcIdxAll = (int*)alloc((size_t)3 * (E + N) * 4);

  int e4 = E >> 2, rem = E & 3;
  int gx = cdiv(e4, 1024);  // 4096 edges per block

  // ---- CSR build for all 3 layers ----
  hipMemsetAsync(cntP, 0, (size_t)3 * NB * PSTR * 4, stream);
  {
    dim3 g(gx, 3);
    bucket_hist<<<g, 256, 0, stream>>>(ei, cntP, e4, rem, E, NB);
  }
  bucket_scan<<<3, 256, 0, stream>>>(cntP, bucketOff, curP, NB, E);
  {
    dim3 g(gx, 3);
    bucket_scatter<<<g, 256, 0, stream>>>(ei, curP, pairsAll, e4, rem, E, NB);
  }
  {
    dim3 g(NB, 3);
    csr_finalize<<<g, 256, 0, stream>>>(pairsAll, bucketOff, indptrAll, srcIdxAll, N, E, NB);
  }

  // ---- layer 1 ----
  gemm_attn<128, 4><<<cdiv(N, 128), 256, 0, stream>>>(x, W1, as1, ad1, bufXL, aS, aD, N);
  aggregate<128, 4, true><<<cdiv(N, 4), 256, 0, stream>>>(
      bufXL, aS, aD, indptrAll, srcIdxAll, b1, bufH, N);
  // ---- layer 2 ----
  gemm_attn<128, 4><<<cdiv(N, 128), 256, 0, stream>>>(bufH, W2, as2, ad2, bufXL, aS, aD, N);
  aggregate<128, 4, true><<<cdiv(N, 4), 256, 0, stream>>>(
      bufXL, aS, aD, indptrAll + (N + 1), srcIdxAll + (size_t)(E + N), b2, bufH, N);
  // ---- layer 3 ----
  gemm_attn<64, 1><<<cdiv(N, 256), 256, 0, stream>>>(bufH, W3, as3, ad3, bufXL, aS, aD, N);
  aggregate<64, 1, false><<<cdiv(N, 4), 256, 0, stream>>>(
      bufXL, aS, aD, indptrAll + 2 * (N + 1), srcIdxAll + (size_t)2 * (E + N), b3,
      (float*)d_out, N);
}

// Round 14
// 342.847 us; speedup vs baseline: 4.3818x; 1.0415x over previous
//
#include <hip/hip_runtime.h>

typedef unsigned short u16;
typedef unsigned int u32;

#define HID 128

static inline int cdiv(long long a, int b) { return (int)((a + b - 1) / b); }

__device__ __forceinline__ float bfbits(u32 u) { union { u32 u; float f; } c; c.u = u; return c.f; }
__device__ __forceinline__ u16 f2bf(float f) {
  union { float f; u32 u; } c; c.f = f;
  u32 u = c.u;
  return (u16)((u + 0x7fffu + ((u >> 16) & 1u)) >> 16);  // RNE
}
__device__ __forceinline__ u32 pack2bf(float a, float b) {
  return (u32)f2bf(a) | ((u32)f2bf(b) << 16);
}

// ---------- GEMM + attention epilogue ----------
// RT=4 rows/thread (was 8): MT halves -> grid doubles to ~3 blocks/CU, fixing
// the 11% occupancy wall (391 blocks was 1.5/CU). LDS 25KB -> 6 blocks/CU cap.
template <int COUT, int HEADS>
__global__ __launch_bounds__(256) void gemm_attn(
    const float* __restrict__ Hin, const float* __restrict__ W,
    const float* __restrict__ attS, const float* __restrict__ attD,
    u16* __restrict__ XL, float* __restrict__ aS, float* __restrict__ aD, int n) {
  constexpr int RT = 4;          // rows per thread
  constexpr int TN = COUT / 8;   // threads along N (16 or 8)
  constexpr int TM = 256 / TN;   // thread-rows (16 or 32)
  constexpr int MT = TM * RT;    // rows per block (64 or 128)
  constexpr int HALF = COUT / 2;
  constexpr int C = COUT / HEADS;
  constexpr bool SAMEHEAD = (HALF < C);

  __shared__ float xs[32][MT + 4];
  __shared__ float ws[32][COUT];

  int t = threadIdx.x;
  int tx = t % TN, ty = t / TN;
  int rowBase = blockIdx.x * MT;

  float acc[RT][8];
#pragma unroll
  for (int r = 0; r < RT; ++r)
#pragma unroll
    for (int c = 0; c < 8; ++c) acc[r][c] = 0.f;

  for (int kb = 0; kb < 4; ++kb) {
    __syncthreads();
    {
      int kg = (t & 7) * 4;
#pragma unroll
      for (int pass = 0; pass < MT / 32; ++pass) {
        int rr = pass * 32 + (t >> 3);
        int grow = rowBase + rr;
        float4 v = make_float4(0.f, 0.f, 0.f, 0.f);
        if (grow < n) v = *(const float4*)(Hin + (size_t)grow * HID + kb * 32 + kg);
        xs[kg + 0][rr] = v.x;
        xs[kg + 1][rr] = v.y;
        xs[kg + 2][rr] = v.z;
        xs[kg + 3][rr] = v.w;
      }
    }
    {
      constexpr int WF = 32 * COUT / 256;
      const float* wp = W + (size_t)kb * 32 * COUT;
      float* wsf = &ws[0][0];
#pragma unroll
      for (int u = 0; u < WF; u += 4) {
        int idx = t * WF + u;
        *(float4*)(wsf + idx) = *(const float4*)(wp + idx);
      }
    }
    __syncthreads();
#pragma unroll 8
    for (int k = 0; k < 32; ++k) {
      const float4 xv0 = *(const float4*)&xs[k][ty * RT];
      const float4 wv0 = *(const float4*)&ws[k][tx * 4];
      const float4 wv1 = *(const float4*)&ws[k][HALF + tx * 4];
      const float xr[RT] = {xv0.x, xv0.y, xv0.z, xv0.w};
      const float wc[8] = {wv0.x, wv0.y, wv0.z, wv0.w, wv1.x, wv1.y, wv1.z, wv1.w};
#pragma unroll
      for (int r = 0; r < RT; ++r)
#pragma unroll
        for (int c = 0; c < 8; ++c) acc[r][c] += xr[r] * wc[c];
    }
  }

  float sv[8], dv[8];
#pragma unroll
  for (int j = 0; j < 4; ++j) {
    sv[j] = attS[tx * 4 + j];
    sv[4 + j] = attS[HALF + tx * 4 + j];
    dv[j] = attD[tx * 4 + j];
    dv[4 + j] = attD[HALF + tx * 4 + j];
  }
  int row0 = rowBase + ty * RT;
  int hlo = (tx * 4) / C;
  int hhi = (HALF + tx * 4) / C;
  u32* XLo = (u32*)XL;
#pragma unroll
  for (int r = 0; r < RT; ++r) {
    int row = row0 + r;
    bool ok = (row < n);
    if (ok) {
      u32 lo01 = pack2bf(acc[r][0], acc[r][1]);
      u32 lo23 = pack2bf(acc[r][2], acc[r][3]);
      u32 hi01 = pack2bf(acc[r][4], acc[r][5]);
      u32 hi23 = pack2bf(acc[r][6], acc[r][7]);
      *(uint2*)(XLo + (size_t)row * (COUT / 2) + tx * 2) = make_uint2(lo01, lo23);
      *(uint2*)(XLo + (size_t)row * (COUT / 2) + COUT / 4 + tx * 2) = make_uint2(hi01, hi23);
    }
    float pslo = acc[r][0] * sv[0] + acc[r][1] * sv[1] + acc[r][2] * sv[2] + acc[r][3] * sv[3];
    float pshi = acc[r][4] * sv[4] + acc[r][5] * sv[5] + acc[r][6] * sv[6] + acc[r][7] * sv[7];
    float pdlo = acc[r][0] * dv[0] + acc[r][1] * dv[1] + acc[r][2] * dv[2] + acc[r][3] * dv[3];
    float pdhi = acc[r][4] * dv[4] + acc[r][5] * dv[5] + acc[r][6] * dv[6] + acc[r][7] * dv[7];
    if (SAMEHEAD) { pslo += pshi; pdlo += pdhi; }
#pragma unroll
    for (int mk = 1; mk < 8; mk <<= 1) {
      pslo += __shfl_xor(pslo, mk);
      pdlo += __shfl_xor(pdlo, mk);
      if (!SAMEHEAD) {
        pshi += __shfl_xor(pshi, mk);
        pdhi += __shfl_xor(pdhi, mk);
      }
    }
    if (((tx & 7) == 0) && ok) {
      aS[(size_t)row * HEADS + hlo] = pslo;
      aD[(size_t)row * HEADS + hlo] = pdlo;
      if (!SAMEHEAD) {
        aS[(size_t)row * HEADS + hhi] = pshi;
        aD[(size_t)row * HEADS + hhi] = pdhi;
      }
    }
  }
}

// ============ bucket-sort CSR build (unchanged) ============
#define PSTR 16  // padding stride (ints) for per-bucket counters

__global__ __launch_bounds__(256) void bucket_hist(const int* __restrict__ ei,
                                                   int* __restrict__ cntP,
                                                   int e4, int rem, int E, int NB) {
  int L = blockIdx.y;
  const int* dst = ei + (size_t)(2 * L + 1) * E;
  __shared__ int cnt[256];
  int t = threadIdx.x;
  cnt[t] = 0;
  __syncthreads();
  int gbase = blockIdx.x * 1024 + t;
#pragma unroll
  for (int u = 0; u < 4; ++u) {
    int g = gbase + u * 256;
    if (g < e4) {
      int4 d = *(const int4*)(dst + g * 4);
      atomicAdd(&cnt[d.x >> 8], 1);
      atomicAdd(&cnt[d.y >> 8], 1);
      atomicAdd(&cnt[d.z >> 8], 1);
      atomicAdd(&cnt[d.w >> 8], 1);
    }
  }
  if (blockIdx.x == 0 && t < rem) atomicAdd(&cnt[dst[e4 * 4 + t] >> 8], 1);
  __syncthreads();
  int c = cnt[t];
  if (t < NB && c > 0) atomicAdd(&cntP[(L * NB + t) * PSTR], c);
}

__global__ __launch_bounds__(256) void bucket_scan(const int* __restrict__ cntP,
                                                   int* __restrict__ bucketOff,
                                                   int* __restrict__ curP, int NB, int E) {
  int L = blockIdx.x;
  int t = threadIdx.x;
  int lane = t & 63, wid = t >> 6;
  __shared__ int wpart[4];
  int v = (t < NB) ? cntP[(L * NB + t) * PSTR] : 0;
  int inc = v;
#pragma unroll
  for (int off = 1; off < 64; off <<= 1) {
    int w = __shfl_up(inc, (unsigned)off, 64);
    if (lane >= off) inc += w;
  }
  if (lane == 63) wpart[wid] = inc;
  __syncthreads();
  if (t == 0) {
    int a = 0;
#pragma unroll
    for (int k = 0; k < 4; ++k) { int tmp = wpart[k]; wpart[k] = a; a += tmp; }
  }
  __syncthreads();
  int ex = wpart[wid] + inc - v;
  if (t < NB) {
    bucketOff[L * (NB + 1) + t] = ex;
    curP[(L * NB + t) * PSTR] = ex;
  }
  if (t == 0) bucketOff[L * (NB + 1) + NB] = E;
}

__global__ __launch_bounds__(256) void bucket_scatter(const int* __restrict__ ei,
                                                      int* __restrict__ curP,
                                                      int2* __restrict__ pairsAll,
                                                      int e4, int rem, int E, int NB) {
  int L = blockIdx.y;
  const int* src = ei + (size_t)(2 * L) * E;
  const int* dst = src + E;
  int2* pairs = pairsAll + (size_t)L * E;
  __shared__ int cnt[256];
  __shared__ int baseS[256];
  int t = threadIdx.x;
  cnt[t] = 0;
  __syncthreads();

  int gbase = blockIdx.x * 1024 + t;
  int4 dv[4], sv[4];
  bool val[4];
#pragma unroll
  for (int u = 0; u < 4; ++u) {
    int g = gbase + u * 256;
    val[u] = (g < e4);
    if (val[u]) {
      dv[u] = *(const int4*)(dst + g * 4);
      sv[u] = *(const int4*)(src + g * 4);
      atomicAdd(&cnt[dv[u].x >> 8], 1);
      atomicAdd(&cnt[dv[u].y >> 8], 1);
      atomicAdd(&cnt[dv[u].z >> 8], 1);
      atomicAdd(&cnt[dv[u].w >> 8], 1);
    }
  }
  int tailS = 0, tailD = 0;
  bool hasTail = (blockIdx.x == 0 && t < rem);
  if (hasTail) {
    tailD = dst[e4 * 4 + t];
    tailS = src[e4 * 4 + t];
    atomicAdd(&cnt[tailD >> 8], 1);
  }
  __syncthreads();
  int c = cnt[t];
  if (t < NB && c > 0) baseS[t] = atomicAdd(&curP[(L * NB + t) * PSTR], c);
  __syncthreads();
  cnt[t] = 0;  // reuse as local offset
  __syncthreads();
#pragma unroll
  for (int u = 0; u < 4; ++u) {
    if (val[u]) {
      int b, p;
      b = dv[u].x >> 8; p = atomicAdd(&cnt[b], 1); pairs[baseS[b] + p] = make_int2(sv[u].x, dv[u].x);
      b = dv[u].y >> 8; p = atomicAdd(&cnt[b], 1); pairs[baseS[b] + p] = make_int2(sv[u].y, dv[u].y);
      b = dv[u].z >> 8; p = atomicAdd(&cnt[b], 1); pairs[baseS[b] + p] = make_int2(sv[u].z, dv[u].z);
      b = dv[u].w >> 8; p = atomicAdd(&cnt[b], 1); pairs[baseS[b] + p] = make_int2(sv[u].w, dv[u].w);
    }
  }
  if (hasTail) {
    int b = tailD >> 8;
    int p = atomicAdd(&cnt[b], 1);
    pairs[baseS[b] + p] = make_int2(tailS, tailD);
  }
}

__global__ __launch_bounds__(256) void csr_finalize(const int2* __restrict__ pairsAll,
                                                    const int* __restrict__ bucketOff,
                                                    int* __restrict__ indptrAll,
                                                    int* __restrict__ srcIdxAll,
                                                    int N, int E, int NB) {
  int L = blockIdx.y, b = blockIdx.x;
  const int2* pairs = pairsAll + (size_t)L * E;
  int* indptr = indptrAll + (size_t)L * (N + 1);
  int* srcL = srcIdxAll + (size_t)L * (E + N);
  int base = b << 8;
  int nodes = min(256, N - base);
  int p0 = bucketOff[L * (NB + 1) + b];
  int p1 = bucketOff[L * (NB + 1) + b + 1];

  __shared__ int cnt[256];
  __shared__ int wpart[4];
  int t = threadIdx.x;
  int lane = t & 63, wid = t >> 6;
  cnt[t] = 0;
  __syncthreads();

  for (int i = p0 + t; i < p1; i += 256) atomicAdd(&cnt[pairs[i].y - base], 1);
  __syncthreads();

  int v = (t < nodes) ? cnt[t] + 1 : 0;
  int inc = v;
#pragma unroll
  for (int off = 1; off < 64; off <<= 1) {
    int w = __shfl_up(inc, (unsigned)off, 64);
    if (lane >= off) inc += w;
  }
  if (lane == 63) wpart[wid] = inc;
  __syncthreads();
  if (t == 0) {
    int a = 0;
#pragma unroll
    for (int k = 0; k < 4; ++k) { int tmp = wpart[k]; wpart[k] = a; a += tmp; }
  }
  __syncthreads();
  int ex = wpart[wid] + inc - v;
  __syncthreads();
  if (t < nodes) {
    int segStart = p0 + base + ex;
    indptr[base + t] = segStart;
    srcL[segStart] = base + t;
    cnt[t] = segStart + 1;
  }
  if (b == NB - 1 && t == 0) indptr[N] = E + N;
  __syncthreads();

  for (int i = p0 + t; i < p1; i += 256) {
    int2 pr = pairs[i];
    int p = atomicAdd(&cnt[pr.y - base], 1);
    srcL[p] = pr.x;
  }
}

// ---------- aggregation: wave = node, G edges per instruction (unchanged) ----------
template <int COUT, int HEADS, bool RELU>
__global__ __launch_bounds__(256) void aggregate(
    const u16* __restrict__ XL, const float* __restrict__ aS, const float* __restrict__ aD,
    const int* __restrict__ indptr, const int* __restrict__ srcIdx,
    const float* __restrict__ bias, float* __restrict__ outF, int n) {
  constexpr int VPL = 8;           // cols per lane
  constexpr int LPG = COUT / VPL;  // lanes per edge-group (16 or 8)
  constexpr int G = 64 / LPG;      // edges per batch (4 or 8)
  constexpr int C = COUT / HEADS;
  int wave = (blockIdx.x * blockDim.x + threadIdx.x) >> 6;
  if (wave >= n) return;
  int lane = threadIdx.x & 63;
  int g = lane / LPG;
  int cl = lane % LPG;
  int col0 = cl * VPL;
  int h = col0 / C;
  int i = wave;
  float ad = aD[i * HEADS + h];
  float s = 0.f;
  float acc[VPL];
#pragma unroll
  for (int v = 0; v < VPL; ++v) acc[v] = 0.f;
  int e0 = indptr[i], e1 = indptr[i + 1];
  const u32* XL32 = (const u32*)XL;

  auto doEdge = [&](int loadIdx, bool act) {
    int j = srcIdx[loadIdx];  // broadcast within group
    float a = aS[j * HEADS + h];
    uint4 px = *(const uint4*)(XL32 + j * (COUT / 2) + cl * 4);
    float l = a + ad;
    l = (l >= 0.f) ? l : 0.2f * l;
    float el = act ? __expf(fminf(l, 60.f)) : 0.f;
    s += el;
    acc[0] += el * bfbits(px.x << 16);
    acc[1] += el * bfbits(px.x & 0xffff0000u);
    acc[2] += el * bfbits(px.y << 16);
    acc[3] += el * bfbits(px.y & 0xffff0000u);
    acc[4] += el * bfbits(px.z << 16);
    acc[5] += el * bfbits(px.z & 0xffff0000u);
    acc[6] += el * bfbits(px.w << 16);
    acc[7] += el * bfbits(px.w & 0xffff0000u);
  };

  int idx = e0;
  for (; idx + 2 * G <= e1; idx += 2 * G) {
    doEdge(idx + g, true);
    doEdge(idx + G + g, true);
  }
  for (; idx + G <= e1; idx += G) doEdge(idx + g, true);
  int r = e1 - idx;
  if (r > 0) doEdge((g < r) ? (idx + g) : e0, g < r);

#pragma unroll
  for (int mk = LPG; mk < 64; mk <<= 1) {
    s += __shfl_xor(s, mk);
#pragma unroll
    for (int v = 0; v < VPL; ++v) acc[v] += __shfl_xor(acc[v], mk);
  }

  if (g == 0) {
    float inv = 1.f / (s + 1e-16f);
    float o[VPL];
#pragma unroll
    for (int v = 0; v < VPL; ++v) {
      o[v] = acc[v] * inv + bias[col0 + v];
      if (RELU) o[v] = fmaxf(o[v], 0.f);
    }
    float* op = outF + (size_t)i * COUT + col0;
    *(float4*)op = make_float4(o[0], o[1], o[2], o[3]);
    *(float4*)(op + 4) = make_float4(o[4], o[5], o[6], o[7]);
  }
}

extern "C" void kernel_launch(void* const* d_in, const int* in_sizes, int n_in,
                              void* d_out, int out_size, void* d_ws, size_t ws_size,
                              hipStream_t stream) {
  const float* x = (const float*)d_in[0];
  const int* ei = (const int*)d_in[1];
  const float* W1 = (const float*)d_in[2];
  const float* as1 = (const float*)d_in[3];
  const float* ad1 = (const float*)d_in[4];
  const float* b1 = (const float*)d_in[5];
  const float* W2 = (const float*)d_in[6];
  const float* as2 = (const float*)d_in[7];
  const float* ad2 = (const float*)d_in[8];
  const float* b2 = (const float*)d_in[9];
  const float* W3 = (const float*)d_in[10];
  const float* as3 = (const float*)d_in[11];
  const float* ad3 = (const float*)d_in[12];
  const float* b3 = (const float*)d_in[13];

  int N = in_sizes[0] / HID;  // x is [N,128]
  int E = in_sizes[1] / 6;    // edge_indices is [3,2,E]
  int NB = cdiv(N, 256);      // buckets of 256 nodes (NB <= 256 assumed)

  char* w = (char*)d_ws;
  auto alloc = [&](size_t bytes) {
    void* q = (void*)w;
    w += (bytes + 255) & ~(size_t)255;
    return q;
  };
  float* bufH = (float*)alloc((size_t)N * HID * 4);
  u16* bufXL = (u16*)alloc((size_t)N * HID * 2);
  float* aS = (float*)alloc((size_t)N * 4 * 4);
  float* aD = (float*)alloc((size_t)N * 4 * 4);
  int* cntP = (int*)alloc((size_t)3 * NB * PSTR * 4);
  int* curP = (int*)alloc((size_t)3 * NB * PSTR * 4);
  int* bucketOff = (int*)alloc((size_t)3 * (NB + 1) * 4);
  int2* pairsAll = (int2*)alloc((size_t)3 * E * 8);
  int* indptrAll = (int*)alloc((size_t)3 * (N + 1) * 4);
  int* srcIdxAll = (int*)alloc((size_t)3 * (E + N) * 4);

  int e4 = E >> 2, rem = E & 3;
  int gx = cdiv(e4, 1024);  // 4096 edges per block

  // ---- CSR build for all 3 layers ----
  hipMemsetAsync(cntP, 0, (size_t)3 * NB * PSTR * 4, stream);
  {
    dim3 g(gx, 3);
    bucket_hist<<<g, 256, 0, stream>>>(ei, cntP, e4, rem, E, NB);
  }
  bucket_scan<<<3, 256, 0, stream>>>(cntP, bucketOff, curP, NB, E);
  {
    dim3 g(gx, 3);
    bucket_scatter<<<g, 256, 0, stream>>>(ei, curP, pairsAll, e4, rem, E, NB);
  }
  {
    dim3 g(NB, 3);
    csr_finalize<<<g, 256, 0, stream>>>(pairsAll, bucketOff, indptrAll, srcIdxAll, N, E, NB);
  }

  // ---- layer 1 ----
  gemm_attn<128, 4><<<cdiv(N, 64), 256, 0, stream>>>(x, W1, as1, ad1, bufXL, aS, aD, N);
  aggregate<128, 4, true><<<cdiv(N, 4), 256, 0, stream>>>(
      bufXL, aS, aD, indptrAll, srcIdxAll, b1, bufH, N);
  // ---- layer 2 ----
  gemm_attn<128, 4><<<cdiv(N, 64), 256, 0, stream>>>(bufH, W2, as2, ad2, bufXL, aS, aD, N);
  aggregate<128, 4, true><<<cdiv(N, 4), 256, 0, stream>>>(
      bufXL, aS, aD, indptrAll + (N + 1), srcIdxAll + (size_t)(E + N), b2, bufH, N);
  // ---- layer 3 ----
  gemm_attn<64, 1><<<cdiv(N, 128), 256, 0, stream>>>(bufH, W3, as3, ad3, bufXL, aS, aD, N);
  aggregate<64, 1, false><<<cdiv(N, 4), 256, 0, stream>>>(
      bufXL, aS, aD, indptrAll + 2 * (N + 1), srcIdxAll + (size_t)2 * (E + N), b3,
      (float*)d_out, N);
}